// Round 2
// baseline (172.648 us; speedup 1.0000x reference)
//
#include <hip/hip_runtime.h>
#include <math.h>

#define MU_MAXC 32
#define MV_MAXC 32
#define OUT_UC  64
#define OUT_VC  64
#define DEG     3
#define NKNOT   (MU_MAXC + DEG + 1)   // 36
#define EPSV    1e-5f
#define TROW    33   // float4 quads per tmp row (32 data + 1 pad)
#define UH      32   // u-rows per block (half a sample)

__global__ void zero_ws_kernel(double* acc, int* bad) {
    acc[0] = 0.0; acc[1] = 0.0; acc[2] = 0.0; bad[0] = 0;
}

// Clamped open-uniform knot value (padded k >= L-1-DEG clamps to 1.0).
__device__ __forceinline__ float kv_at(int k, int L) {
    return (k <= DEG) ? 0.f : ((k >= L - 1 - DEG) ? 1.f : (float)k / (float)(L - 1));
}

// Cox-de Boor weights for grid index gidx (0..63) with knot count L.
// Span via 5-step binary climb over the monotone predicate kv_at(k)<=uu:
// bit-identical span to the 31-step linear scan (kv_at monotone in k), but
// 5 full-precision fdivs instead of 31. invSum folded into the weights.
__device__ __forceinline__ void cdb_weights(int gidx, int L, float w[4], int* offp)
{
    const float step = (1.f - 2.f * EPSV) / 63.f;
    const float uu = (gidx == 63) ? (1.f - EPSV) : (EPSV + step * (float)gidx);
    int span = DEG;
    #pragma unroll
    for (int s = 16; s >= 1; s >>= 1) {
        const int k = span + s;
        if (k <= NKNOT - 2 && kv_at(k, L) <= uu) span = k;
    }
    float left[DEG + 1], right[DEG + 1];
    #pragma unroll
    for (int j = 1; j <= DEG; j++) {
        left[j]  = uu - kv_at(span + 1 - j, L);
        right[j] = kv_at(span + j, L) - uu;
    }
    float N4[DEG + 1];
    N4[0] = 1.f;
    #pragma unroll
    for (int j = 1; j <= DEG; j++) {
        float saved = 0.f;
        #pragma unroll
        for (int r = 0; r < j; r++) {
            const float temp = N4[r] / (right[r + 1] + left[j - r]);
            N4[r] = saved + right[r + 1] * temp;
            saved = left[j - r] * temp;
        }
        N4[j] = saved;
    }
    const float invs = 1.f / (N4[0] + N4[1] + N4[2] + N4[3]);
    w[0] = N4[0] * invs; w[1] = N4[1] * invs;
    w[2] = N4[2] * invs; w[3] = N4[3] * invs;
    *offp = span - DEG;                               // in [0, 28]
}

// One block per HALF sample. MODE 0: per-block partials + fence/ticket fused
// finalize in the last block (counter zeroed by an 8B hipMemsetAsync — this
// replaced the separate finalize dispatch; its reduction order is identical
// to the old finalize kernel so the output is bitwise unchanged).
// MODE 1: atomic fallback (3-dispatch path), kept for small-ws safety.
// Phase C is merged into C2: every thread computes its own Bu weights
// (binary-climb span makes the duplication net-cheaper than R1's 31-div
// chain on 128 threads), removing s_Bu4/s_uoff and one __syncthreads.
template <int MODE>
__launch_bounds__(256)
__global__ void nurbs_loss_kernel(const float* __restrict__ ctrl_pred,
                                  const float* __restrict__ ctrl_gt,
                                  const float* __restrict__ mask,
                                  const float* __restrict__ xyz,
                                  double* __restrict__ pd, int Bcnt,
                                  unsigned int* __restrict__ ctr,
                                  int* __restrict__ badflag,
                                  float* __restrict__ out)
{
    const int g  = blockIdx.x;
    const int NB = gridDim.x;
    int b, h;
    if ((NB & 15) == 0) {
        // xcd = blockIdx % 8; keep both halves of a sample on one XCD.
        const int slot = g >> 3, xcd = g & 7;
        b = (slot >> 1) * 8 + xcd;
        h = slot & 1;
    } else { b = g >> 1; h = g & 1; }
    const int tid = threadIdx.x;

    __shared__ __align__(16) float s_tmp[UH * TROW * 4];  // 16.9 KB padded quads
    __shared__ __align__(16) float s_Bv4[OUT_VC * 4];     // [v][r], /sumBv folded
    __shared__ int   s_voff[OUT_VC];
    __shared__ int   s_bad, s_last;
    __shared__ float s_mred[4], s_dred[4], s_sred[4];
    __shared__ int   s_rowcnt[4];
    __shared__ unsigned int s_colmask[4];

    if (tid == 0) { s_bad = 0; s_last = 0; }

    // ---- Phase A: mask ballots (full mask -> mu/mv identical in both halves)
    //      + masked ctrl MSE on this block's half of the cells. ----
    float lsum_mask = 0.f, lsum_diff = 0.f;
    unsigned long long bx, by, bz, bw;
    {
        const float4 mm = ((const float4*)(mask + (size_t)b * 1024))[tid];
        bx = __ballot(mm.x > 0.f);
        by = __ballot(mm.y > 0.f);
        bz = __ballot(mm.z > 0.f);
        bw = __ballot(mm.w > 0.f);
        if (h == 0) lsum_mask = mm.x + mm.y + mm.z + mm.w;  // count mask once
    }
    if (tid < 128) {
        const float4 mm2 = ((const float4*)(mask + (size_t)b * 1024))[h * 128 + tid];
        const float4* p4 = (const float4*)(ctrl_pred + (size_t)b * 3072 + (size_t)h * 1536);
        const float4* g4 = (const float4*)(ctrl_gt   + (size_t)b * 3072 + (size_t)h * 1536);
        const float4 pa = p4[3 * tid + 0], pb = p4[3 * tid + 1], pc = p4[3 * tid + 2];
        const float4 ga = g4[3 * tid + 0], gb = g4[3 * tid + 1], gc = g4[3 * tid + 2];
        const float a0 = pa.x - ga.x, a1 = pa.y - ga.y, a2 = pa.z - ga.z;
        const float b0 = pa.w - ga.w, b1 = pb.x - gb.x, b2 = pb.y - gb.y;
        const float c0 = pb.z - gb.z, c1 = pb.w - gb.w, c2 = pc.x - gc.x;
        const float e0 = pc.y - gc.y, e1 = pc.z - gc.z, e2 = pc.w - gc.w;
        lsum_diff = mm2.x * (a0 * a0 + a1 * a1 + a2 * a2)
                  + mm2.y * (b0 * b0 + b1 * b1 + b2 * b2)
                  + mm2.z * (c0 * c0 + c1 * c1 + c2 * c2)
                  + mm2.w * (e0 * e0 + e1 * e1 + e2 * e2);
    }
    int rowcnt;
    {
        unsigned long long anyb = bx | by | bz | bw;
        unsigned long long t = anyb | (anyb >> 4); t |= t >> 2; t |= t >> 1;
        rowcnt = __popcll(t & 0x0101010101010101ULL);
    }
    bool colany = false;
    {
        const int j = tid & 63;
        if (j < 32) {
            const int comp = j & 3;
            const unsigned long long sel = (comp == 0) ? bx : (comp == 1) ? by
                                          : (comp == 2) ? bz : bw;
            colany = (sel & (0x0101010101010101ULL << (j >> 2))) != 0ULL;
        }
    }
    const unsigned long long cmask = __ballot(colany);   // low 32 bits valid
    #pragma unroll
    for (int off = 32; off > 0; off >>= 1) {
        lsum_mask += __shfl_down(lsum_mask, off);
        lsum_diff += __shfl_down(lsum_diff, off);
    }
    if ((tid & 63) == 0) {
        const int w = tid >> 6;
        s_mred[w] = lsum_mask; s_dred[w] = lsum_diff;
        s_rowcnt[w] = rowcnt;  s_colmask[w] = (unsigned int)cmask;
    }
    __syncthreads();                                     // sync 1

    const int cu_ = s_rowcnt[0] + s_rowcnt[1] + s_rowcnt[2] + s_rowcnt[3];
    const int cv_ = __popc(s_colmask[0] | s_colmask[1] | s_colmask[2] | s_colmask[3]);
    const int mu = cu_ > (DEG + 1) ? cu_ : (DEG + 1);
    const int mv = cv_ > (DEG + 1) ? cv_ : (DEG + 1);

    // ---- Phase C2 (C merged in): every thread computes its own Bu weights
    //      for u = tid>>3; 12 ctrl L2-loads issued first, then the k=0 xyz
    //      prefetch (so C2's vmcnt wait leaves xyz in flight), Bv Cox-de-Boor
    //      (threads 0..63) as VALU work in the load shadow. ----
    const int u_loc = tid >> 3;                          // 0..31 local
    const int m = tid & 7;
    float wu[4]; int uoff;
    cdb_weights(h * UH + u_loc, mu + DEG + 1, wu, &uoff);

    const float4* ctrl4 = (const float4*)(ctrl_pred + (size_t)b * 3072);
    float4 c[12];
    #pragma unroll
    for (int e = 0; e < 3; e++) {
        c[e * 4 + 0] = ctrl4[(uoff + 0) * 24 + m * 3 + e];
        c[e * 4 + 1] = ctrl4[(uoff + 1) * 24 + m * 3 + e];
        c[e * 4 + 2] = ctrl4[(uoff + 2) * 24 + m * 3 + e];
        c[e * 4 + 3] = ctrl4[(uoff + 3) * 24 + m * 3 + e];
    }

    const int vg = (tid & 15) * 4;
    const int ug = tid >> 4;                             // 0..15
    const float* xyzb = xyz + ((size_t)b * 4096 + (size_t)h * 2048) * 3;
    const float4* xA = (const float4*)(xyzb + ((size_t)ug * 64 + vg) * 3);
    const float4 x0 = xA[0], x1 = xA[1], x2 = xA[2];     // k=0 prefetch

    if (tid < 64) {                                      // Bv (VALU, load shadow)
        float wv[4]; int voff;
        cdb_weights(tid, mv + DEG + 1, wv, &voff);
        ((float4*)s_Bv4)[tid] = make_float4(wv[0], wv[1], wv[2], wv[3]);
        s_voff[tid] = voff;
    }

    float f[12];
    #pragma unroll
    for (int e = 0; e < 3; e++) {
        const float4 c0 = c[e * 4 + 0], c1 = c[e * 4 + 1];
        const float4 c2 = c[e * 4 + 2], c3 = c[e * 4 + 3];
        f[e * 4 + 0] = wu[0] * c0.x + wu[1] * c1.x + wu[2] * c2.x + wu[3] * c3.x;
        f[e * 4 + 1] = wu[0] * c0.y + wu[1] * c1.y + wu[2] * c2.y + wu[3] * c3.y;
        f[e * 4 + 2] = wu[0] * c0.z + wu[1] * c1.z + wu[2] * c2.z + wu[3] * c3.z;
        f[e * 4 + 3] = wu[0] * c0.w + wu[1] * c1.w + wu[2] * c2.w + wu[3] * c3.w;
    }
    {
        float4* dst = ((float4*)s_tmp) + (u_loc * TROW + m * 4);
        dst[0] = make_float4(f[0], f[1],  f[2],  0.f);
        dst[1] = make_float4(f[3], f[4],  f[5],  0.f);
        dst[2] = make_float4(f[6], f[7],  f[8],  0.f);
        dst[3] = make_float4(f[9], f[10], f[11], 0.f);
    }
    __syncthreads();                                     // sync 2

    // ---- Phase D: 8 points/thread (2 u x 4 consecutive v); k=1 xyz issued
    //      first so it hides under k=0 compute. 4 ds_read_b128 + 18 VALU/pt. ----
    const float4* xB = (const float4*)(xyzb + ((size_t)(ug + 16) * 64 + vg) * 3);
    const float4 y0 = xB[0], y1 = xB[1], y2 = xB[2];     // k=1 prefetch
    float4 wva[4]; int voa[4];
    #pragma unroll
    for (int q = 0; q < 4; q++) {
        voa[q] = s_voff[vg + q];
        wva[q] = ((const float4*)s_Bv4)[vg + q];
    }
    float lsum_surf = 0.f;

    #define POINT4(TROWP, XA, XB, XC)                                        \
    do {                                                                     \
        const float px[4] = {(XA).x, (XA).w, (XB).z, (XC).y};                \
        const float py[4] = {(XA).y, (XB).x, (XB).w, (XC).z};                \
        const float pz[4] = {(XA).z, (XB).y, (XC).x, (XC).w};                \
        _Pragma("unroll")                                                    \
        for (int q = 0; q < 4; q++) {                                        \
            const float4 t0 = (TROWP)[voa[q] + 0];                           \
            const float4 t1 = (TROWP)[voa[q] + 1];                           \
            const float4 t2 = (TROWP)[voa[q] + 2];                           \
            const float4 t3 = (TROWP)[voa[q] + 3];                           \
            const float4 w = wva[q];                                         \
            const float n0 = w.x * t0.x + w.y * t1.x + w.z * t2.x + w.w * t3.x; \
            const float n1 = w.x * t0.y + w.y * t1.y + w.z * t2.y + w.w * t3.y; \
            const float n2 = w.x * t0.z + w.y * t1.z + w.z * t2.z + w.w * t3.z; \
            const float d0 = n0 - px[q];                                     \
            const float d1 = n1 - py[q];                                     \
            const float d2 = n2 - pz[q];                                     \
            lsum_surf += d0 * d0 + d1 * d1 + d2 * d2;                        \
        }                                                                    \
    } while (0)

    POINT4(((const float4*)s_tmp) + ug * TROW,        x0, x1, x2);
    POINT4(((const float4*)s_tmp) + (ug + 16) * TROW, y0, y1, y2);
    #undef POINT4

    // hoisted non-finite check: any non-finite surf value makes the partial
    // +Inf/NaN (squares never cancel back to finite)
    const int bad = !isfinite(lsum_surf);
    #pragma unroll
    for (int off = 32; off > 0; off >>= 1)
        lsum_surf += __shfl_down(lsum_surf, off);
    if ((tid & 63) == 0) s_sred[tid >> 6] = lsum_surf;
    if (bad) atomicOr(&s_bad, 1);
    __syncthreads();                                     // sync 3

    if (tid == 0) {
        const double surf = (double)s_sred[0] + s_sred[1] + s_sred[2] + s_sred[3];
        const double dsum = (double)s_dred[0] + s_dred[1] + s_dred[2] + s_dred[3];
        const double msum = (double)s_mred[0] + s_mred[1] + s_mred[2] + s_mred[3];
        if (MODE == 0) {
            pd[g]          = dsum;
            pd[NB + g]     = msum;
            pd[2 * NB + g] = surf;
            if (s_bad) atomicOr(badflag, 1);
            __threadfence();                             // release partials
            const unsigned int t = atomicAdd(ctr, 1u);
            s_last = (t == (unsigned int)(NB - 1));
        } else {
            atomicAdd(&pd[0], dsum);
            atomicAdd(&pd[1], msum);
            atomicAdd(&pd[2], surf);
            if (s_bad) atomicOr(badflag, 1);
        }
    }
    if (MODE == 0) {
        __syncthreads();                                 // sync 4 (gate s_last)
        if (s_last) {
            // fused finalize — identical reduction order to the old
            // finalize_partials_kernel => bitwise-identical output.
            __threadfence();                             // acquire partials
            double a0 = 0.0, a1 = 0.0, a2 = 0.0;
            for (int i = tid; i < NB; i += 256) {
                a0 += pd[i]; a1 += pd[NB + i]; a2 += pd[2 * NB + i];
            }
            #pragma unroll
            for (int off = 32; off > 0; off >>= 1) {
                a0 += __shfl_down(a0, off);
                a1 += __shfl_down(a1, off);
                a2 += __shfl_down(a2, off);
            }
            double* sdd = (double*)s_tmp;                // s_tmp is dead here
            if ((tid & 63) == 0) {
                const int w = tid >> 6;
                sdd[w] = a0; sdd[4 + w] = a1; sdd[8 + w] = a2;
            }
            __syncthreads();
            if (tid == 0) {
                double d0 = 0, d1 = 0, d2 = 0;
                #pragma unroll
                for (int i = 0; i < 4; i++) { d0 += sdd[i]; d1 += sdd[4 + i]; d2 += sdd[8 + i]; }
                const int bb = *badflag;
                const double denc = d1 * 3.0;
                const double lc = d0 / (denc > 1.0 ? denc : 1.0);
                const double ls = d2 / ((double)Bcnt * OUT_UC * OUT_VC * 3.0);
                out[0] = (float)(lc + ls);            // total (pre-nan-guard, per ref)
                out[1] = (float)lc;                   // loss_ctrl
                out[2] = bb ? 1.0e6f : (float)ls;     // surf_mse with nan/inf guard
            }
        }
    }
}

__global__ void finalize_atomic_kernel(const double* __restrict__ acc,
                                       const int* __restrict__ bad,
                                       float* __restrict__ out, int Bcnt)
{
    const double denc = acc[1] * 3.0;
    const double lc = acc[0] / (denc > 1.0 ? denc : 1.0);
    const double ls = acc[2] / ((double)Bcnt * OUT_UC * OUT_VC * 3.0);
    out[0] = (float)(lc + ls);
    out[1] = (float)lc;
    out[2] = bad[0] ? 1.0e6f : (float)ls;
}

extern "C" void kernel_launch(void* const* d_in, const int* in_sizes, int n_in,
                              void* d_out, int out_size, void* d_ws, size_t ws_size,
                              hipStream_t stream)
{
    const float* pred = (const float*)d_in[0];
    const float* gt   = (const float*)d_in[1];
    const float* mask = (const float*)d_in[2];
    const float* xyz  = (const float*)d_in[3];
    const int Bcnt = in_sizes[2] / (MU_MAXC * MV_MAXC);   // 1024 samples
    const int NB = 2 * Bcnt;                              // 2 half-sample blocks each

    double* pd = (double*)d_ws;
    float* out = (float*)d_out;

    const size_t need = (size_t)3 * NB * sizeof(double) + 16;
    if (ws_size >= need) {
        unsigned int* ctr = (unsigned int*)((char*)d_ws + (size_t)3 * NB * sizeof(double));
        int* badflag = (int*)(ctr + 1);
        hipMemsetAsync((void*)ctr, 0, 8, stream);         // zero {counter, badflag}
        hipLaunchKernelGGL((nurbs_loss_kernel<0>), dim3(NB), dim3(256), 0, stream,
                           pred, gt, mask, xyz, pd, Bcnt, ctr, badflag, out);
    } else {
        int* badflag = (int*)(pd + 3);
        hipLaunchKernelGGL(zero_ws_kernel, dim3(1), dim3(1), 0, stream, pd, badflag);
        hipLaunchKernelGGL((nurbs_loss_kernel<1>), dim3(NB), dim3(256), 0, stream,
                           pred, gt, mask, xyz, pd, Bcnt, (unsigned int*)nullptr,
                           badflag, out);
        hipLaunchKernelGGL(finalize_atomic_kernel, dim3(1), dim3(1), 0, stream,
                           pd, badflag, out, Bcnt);
    }
}

// Round 4
// 116.340 us; speedup vs baseline: 1.4840x; 1.4840x over previous
//
#include <hip/hip_runtime.h>
#include <math.h>

#define MU_MAXC 32
#define MV_MAXC 32
#define OUT_UC  64
#define OUT_VC  64
#define DEG     3
#define NKNOT   (MU_MAXC + DEG + 1)   // 36
#define EPSV    1e-5f
#define TROW    33   // float4 quads per tmp row (32 data + 1 pad)
#define UH      32   // u-rows per block (half a sample)

__global__ void zero_ws_kernel(double* acc, int* bad) {
    acc[0] = 0.0; acc[1] = 0.0; acc[2] = 0.0; bad[0] = 0;
}

// Clamped open-uniform knot value (padded k >= L-1-DEG clamps to 1.0).
__device__ __forceinline__ float kv_at(int k, int L) {
    return (k <= DEG) ? 0.f : ((k >= L - 1 - DEG) ? 1.f : (float)k / (float)(L - 1));
}

// Cox-de Boor weights for grid index gidx (0..63) with knot count L.
// Span via 5-step binary climb over the monotone predicate kv_at(k)<=uu:
// bit-identical to the 31-step linear scan (R2 passed absmax=0.0 with this),
// 5 full-rate fdivs instead of 31. invSum folded into the weights.
__device__ __forceinline__ void cdb_weights(int gidx, int L, float w[4], int* offp)
{
    const float step = (1.f - 2.f * EPSV) / 63.f;
    const float uu = (gidx == 63) ? (1.f - EPSV) : (EPSV + step * (float)gidx);
    int span = DEG;
    #pragma unroll
    for (int s = 16; s >= 1; s >>= 1) {
        const int k = span + s;
        if (k <= NKNOT - 2 && kv_at(k, L) <= uu) span = k;
    }
    float left[DEG + 1], right[DEG + 1];
    #pragma unroll
    for (int j = 1; j <= DEG; j++) {
        left[j]  = uu - kv_at(span + 1 - j, L);
        right[j] = kv_at(span + j, L) - uu;
    }
    float N4[DEG + 1];
    N4[0] = 1.f;
    #pragma unroll
    for (int j = 1; j <= DEG; j++) {
        float saved = 0.f;
        #pragma unroll
        for (int r = 0; r < j; r++) {
            const float temp = N4[r] / (right[r + 1] + left[j - r]);
            N4[r] = saved + right[r + 1] * temp;
            saved = left[j - r] * temp;
        }
        N4[j] = saved;
    }
    const float invs = 1.f / (N4[0] + N4[1] + N4[2] + N4[3]);
    w[0] = N4[0] * invs; w[1] = N4[1] * invs;
    w[2] = N4[2] * invs; w[3] = N4[3] * invs;
    *offp = span - DEG;                               // in [0, 28]
}

// One block per HALF sample. MODE 0: per-block partials, reduced by a separate
// finalize dispatch. NO device-scope fences in this kernel: R2's fence/ticket
// fused finalize (__threadfence per block) forced per-block L2 writebacks on
// the non-coherent XCD L2s and blew the kernel up 27us -> 100us. Reverted.
// Phase C is merged into C2 (every thread computes its own Bu weights via the
// binary-climb cdb; removes one __syncthreads and the s_Bu4/s_uoff LDS trip).
// Phase-A MSE is owned by the thread already holding the mask quad
// (tid>>7 == h), so no mask re-read and one pred/gt base — bitwise identical
// (per-wave partials shift slots; zeros commute exactly in FP).
template <int MODE>
__launch_bounds__(256)
__global__ void nurbs_loss_kernel(const float* __restrict__ ctrl_pred,
                                  const float* __restrict__ ctrl_gt,
                                  const float* __restrict__ mask,
                                  const float* __restrict__ xyz,
                                  double* __restrict__ pd, int Bcnt,
                                  int* __restrict__ badp)
{
    const int g  = blockIdx.x;
    const int NB = gridDim.x;
    int b, h;
    if ((NB & 15) == 0) {
        // xcd = blockIdx % 8; keep both halves of a sample on one XCD.
        const int slot = g >> 3, xcd = g & 7;
        b = (slot >> 1) * 8 + xcd;
        h = slot & 1;
    } else { b = g >> 1; h = g & 1; }
    const int tid = threadIdx.x;

    __shared__ __align__(16) float s_tmp[UH * TROW * 4];  // 16.9 KB padded quads
    __shared__ __align__(16) float s_Bv4[OUT_VC * 4];     // [v][r], /sumBv folded
    __shared__ int   s_voff[OUT_VC];
    __shared__ int   s_bad;
    __shared__ float s_mred[4], s_dred[4], s_sred[4];
    __shared__ int   s_rowcnt[4];
    __shared__ unsigned int s_colmask[4];

    if (tid == 0) s_bad = 0;

    // ---- Phase A: mask ballots (full mask -> mu/mv identical in both halves)
    //      + masked ctrl MSE on this block's half, by the quad-owning threads. ----
    float lsum_mask = 0.f, lsum_diff = 0.f;
    unsigned long long bx, by, bz, bw;
    {
        const float4 mm = ((const float4*)(mask + (size_t)b * 1024))[tid];
        bx = __ballot(mm.x > 0.f);
        by = __ballot(mm.y > 0.f);
        bz = __ballot(mm.z > 0.f);
        bw = __ballot(mm.w > 0.f);
        if (h == 0) lsum_mask = mm.x + mm.y + mm.z + mm.w;  // count mask once
        if ((tid >> 7) == h) {
            // this thread's mask quad is in its own half: cells 4*tid..4*tid+3
            const float4* p4 = (const float4*)(ctrl_pred + (size_t)b * 3072);
            const float4* g4 = (const float4*)(ctrl_gt   + (size_t)b * 3072);
            const float4 pa = p4[3 * tid + 0], pb = p4[3 * tid + 1], pc = p4[3 * tid + 2];
            const float4 ga = g4[3 * tid + 0], gb = g4[3 * tid + 1], gc = g4[3 * tid + 2];
            const float a0 = pa.x - ga.x, a1 = pa.y - ga.y, a2 = pa.z - ga.z;
            const float b0 = pa.w - ga.w, b1 = pb.x - gb.x, b2 = pb.y - gb.y;
            const float c0 = pb.z - gb.z, c1 = pb.w - gb.w, c2 = pc.x - gc.x;
            const float e0 = pc.y - gc.y, e1 = pc.z - gc.z, e2 = pc.w - gc.w;
            lsum_diff = mm.x * (a0 * a0 + a1 * a1 + a2 * a2)
                      + mm.y * (b0 * b0 + b1 * b1 + b2 * b2)
                      + mm.z * (c0 * c0 + c1 * c1 + c2 * c2)
                      + mm.w * (e0 * e0 + e1 * e1 + e2 * e2);
        }
    }
    int rowcnt;
    {
        unsigned long long anyb = bx | by | bz | bw;
        unsigned long long t = anyb | (anyb >> 4); t |= t >> 2; t |= t >> 1;
        rowcnt = __popcll(t & 0x0101010101010101ULL);
    }
    bool colany = false;
    {
        const int j = tid & 63;
        if (j < 32) {
            const int comp = j & 3;
            const unsigned long long sel = (comp == 0) ? bx : (comp == 1) ? by
                                          : (comp == 2) ? bz : bw;
            colany = (sel & (0x0101010101010101ULL << (j >> 2))) != 0ULL;
        }
    }
    const unsigned long long cmask = __ballot(colany);   // low 32 bits valid
    #pragma unroll
    for (int off = 32; off > 0; off >>= 1) {
        lsum_mask += __shfl_down(lsum_mask, off);
        lsum_diff += __shfl_down(lsum_diff, off);
    }
    if ((tid & 63) == 0) {
        const int w = tid >> 6;
        s_mred[w] = lsum_mask; s_dred[w] = lsum_diff;
        s_rowcnt[w] = rowcnt;  s_colmask[w] = (unsigned int)cmask;
    }
    __syncthreads();                                     // sync 1

    const int cu_ = s_rowcnt[0] + s_rowcnt[1] + s_rowcnt[2] + s_rowcnt[3];
    const int cv_ = __popc(s_colmask[0] | s_colmask[1] | s_colmask[2] | s_colmask[3]);
    const int mu = cu_ > (DEG + 1) ? cu_ : (DEG + 1);
    const int mv = cv_ > (DEG + 1) ? cv_ : (DEG + 1);

    // ---- Phase C2 (C merged in): every thread computes its own Bu weights
    //      for u = tid>>3; 12 ctrl L2-loads issued first, then the k=0 xyz
    //      prefetch (so C2's vmcnt wait leaves xyz in flight), Bv Cox-de-Boor
    //      (threads 0..63) as VALU work in the load shadow. ----
    const int u_loc = tid >> 3;                          // 0..31 local
    const int m = tid & 7;
    float wu[4]; int uoff;
    cdb_weights(h * UH + u_loc, mu + DEG + 1, wu, &uoff);

    const float4* ctrl4 = (const float4*)(ctrl_pred + (size_t)b * 3072);
    float4 c[12];
    #pragma unroll
    for (int e = 0; e < 3; e++) {
        c[e * 4 + 0] = ctrl4[(uoff + 0) * 24 + m * 3 + e];
        c[e * 4 + 1] = ctrl4[(uoff + 1) * 24 + m * 3 + e];
        c[e * 4 + 2] = ctrl4[(uoff + 2) * 24 + m * 3 + e];
        c[e * 4 + 3] = ctrl4[(uoff + 3) * 24 + m * 3 + e];
    }

    const int vg = (tid & 15) * 4;
    const int ug = tid >> 4;                             // 0..15
    const float* xyzb = xyz + ((size_t)b * 4096 + (size_t)h * 2048) * 3;
    const float4* xA = (const float4*)(xyzb + ((size_t)ug * 64 + vg) * 3);
    const float4 x0 = xA[0], x1 = xA[1], x2 = xA[2];     // k=0 prefetch

    if (tid < 64) {                                      // Bv (VALU, load shadow)
        float wv[4]; int voff;
        cdb_weights(tid, mv + DEG + 1, wv, &voff);
        ((float4*)s_Bv4)[tid] = make_float4(wv[0], wv[1], wv[2], wv[3]);
        s_voff[tid] = voff;
    }

    float f[12];
    #pragma unroll
    for (int e = 0; e < 3; e++) {
        const float4 c0 = c[e * 4 + 0], c1 = c[e * 4 + 1];
        const float4 c2 = c[e * 4 + 2], c3 = c[e * 4 + 3];
        f[e * 4 + 0] = wu[0] * c0.x + wu[1] * c1.x + wu[2] * c2.x + wu[3] * c3.x;
        f[e * 4 + 1] = wu[0] * c0.y + wu[1] * c1.y + wu[2] * c2.y + wu[3] * c3.y;
        f[e * 4 + 2] = wu[0] * c0.z + wu[1] * c1.z + wu[2] * c2.z + wu[3] * c3.z;
        f[e * 4 + 3] = wu[0] * c0.w + wu[1] * c1.w + wu[2] * c2.w + wu[3] * c3.w;
    }
    {
        float4* dst = ((float4*)s_tmp) + (u_loc * TROW + m * 4);
        dst[0] = make_float4(f[0], f[1],  f[2],  0.f);
        dst[1] = make_float4(f[3], f[4],  f[5],  0.f);
        dst[2] = make_float4(f[6], f[7],  f[8],  0.f);
        dst[3] = make_float4(f[9], f[10], f[11], 0.f);
    }
    __syncthreads();                                     // sync 2

    // ---- Phase D: 8 points/thread (2 u x 4 consecutive v); k=1 xyz issued
    //      first so it hides under k=0 compute. 4 ds_read_b128 + 18 VALU/pt. ----
    const float4* xB = (const float4*)(xyzb + ((size_t)(ug + 16) * 64 + vg) * 3);
    const float4 y0 = xB[0], y1 = xB[1], y2 = xB[2];     // k=1 prefetch
    float4 wva[4]; int voa[4];
    #pragma unroll
    for (int q = 0; q < 4; q++) {
        voa[q] = s_voff[vg + q];
        wva[q] = ((const float4*)s_Bv4)[vg + q];
    }
    float lsum_surf = 0.f;

    #define POINT4(TROWP, XA, XB, XC)                                        \
    do {                                                                     \
        const float px[4] = {(XA).x, (XA).w, (XB).z, (XC).y};                \
        const float py[4] = {(XA).y, (XB).x, (XB).w, (XC).z};                \
        const float pz[4] = {(XA).z, (XB).y, (XC).x, (XC).w};                \
        _Pragma("unroll")                                                    \
        for (int q = 0; q < 4; q++) {                                        \
            const float4 t0 = (TROWP)[voa[q] + 0];                           \
            const float4 t1 = (TROWP)[voa[q] + 1];                           \
            const float4 t2 = (TROWP)[voa[q] + 2];                           \
            const float4 t3 = (TROWP)[voa[q] + 3];                           \
            const float4 w = wva[q];                                         \
            const float n0 = w.x * t0.x + w.y * t1.x + w.z * t2.x + w.w * t3.x; \
            const float n1 = w.x * t0.y + w.y * t1.y + w.z * t2.y + w.w * t3.y; \
            const float n2 = w.x * t0.z + w.y * t1.z + w.z * t2.z + w.w * t3.z; \
            const float d0 = n0 - px[q];                                     \
            const float d1 = n1 - py[q];                                     \
            const float d2 = n2 - pz[q];                                     \
            lsum_surf += d0 * d0 + d1 * d1 + d2 * d2;                        \
        }                                                                    \
    } while (0)

    POINT4(((const float4*)s_tmp) + ug * TROW,        x0, x1, x2);
    POINT4(((const float4*)s_tmp) + (ug + 16) * TROW, y0, y1, y2);
    #undef POINT4

    // hoisted non-finite check: any non-finite surf value makes the partial
    // +Inf/NaN (squares never cancel back to finite)
    const int bad = !isfinite(lsum_surf);
    #pragma unroll
    for (int off = 32; off > 0; off >>= 1)
        lsum_surf += __shfl_down(lsum_surf, off);
    if ((tid & 63) == 0) s_sred[tid >> 6] = lsum_surf;
    if (bad) atomicOr(&s_bad, 1);
    __syncthreads();                                     // sync 3

    if (tid == 0) {
        const double surf = (double)s_sred[0] + s_sred[1] + s_sred[2] + s_sred[3];
        const double dsum = (double)s_dred[0] + s_dred[1] + s_dred[2] + s_dred[3];
        const double msum = (double)s_mred[0] + s_mred[1] + s_mred[2] + s_mred[3];
        if (MODE == 0) {
            pd[g]          = dsum;
            pd[NB + g]     = msum;
            pd[2 * NB + g] = surf;
            badp[g]        = s_bad;
        } else {
            atomicAdd(&pd[0], dsum);
            atomicAdd(&pd[1], msum);
            atomicAdd(&pd[2], surf);
            if (s_bad) atomicOr(badp, 1);
        }
    }
}

__global__ void finalize_partials_kernel(const double* __restrict__ pd,
                                         const int* __restrict__ badp,
                                         float* __restrict__ out, int Bcnt, int NB)
{
    __shared__ double sd0[4], sd1[4], sd2[4];
    __shared__ int sb[4];
    const int tid = threadIdx.x;
    double a0 = 0.0, a1 = 0.0, a2 = 0.0; int bad = 0;
    for (int i = tid; i < NB; i += 256) {
        a0 += pd[i]; a1 += pd[NB + i]; a2 += pd[2 * NB + i];
        bad |= badp[i];
    }
    #pragma unroll
    for (int off = 32; off > 0; off >>= 1) {
        a0 += __shfl_down(a0, off);
        a1 += __shfl_down(a1, off);
        a2 += __shfl_down(a2, off);
        bad |= __shfl_down(bad, off);
    }
    if ((tid & 63) == 0) { const int w = tid >> 6; sd0[w] = a0; sd1[w] = a1; sd2[w] = a2; sb[w] = bad; }
    __syncthreads();
    if (tid == 0) {
        double d0 = 0, d1 = 0, d2 = 0; int bb = 0;
        #pragma unroll
        for (int i = 0; i < 4; i++) { d0 += sd0[i]; d1 += sd1[i]; d2 += sd2[i]; bb |= sb[i]; }
        const double denc = d1 * 3.0;
        const double lc = d0 / (denc > 1.0 ? denc : 1.0);
        const double ls = d2 / ((double)Bcnt * OUT_UC * OUT_VC * 3.0);
        out[0] = (float)(lc + ls);            // total (pre-nan-guard, per ref)
        out[1] = (float)lc;                   // loss_ctrl
        out[2] = bb ? 1.0e6f : (float)ls;     // surf_mse with nan/inf guard
    }
}

__global__ void finalize_atomic_kernel(const double* __restrict__ acc,
                                       const int* __restrict__ bad,
                                       float* __restrict__ out, int Bcnt)
{
    const double denc = acc[1] * 3.0;
    const double lc = acc[0] / (denc > 1.0 ? denc : 1.0);
    const double ls = acc[2] / ((double)Bcnt * OUT_UC * OUT_VC * 3.0);
    out[0] = (float)(lc + ls);
    out[1] = (float)lc;
    out[2] = bad[0] ? 1.0e6f : (float)ls;
}

extern "C" void kernel_launch(void* const* d_in, const int* in_sizes, int n_in,
                              void* d_out, int out_size, void* d_ws, size_t ws_size,
                              hipStream_t stream)
{
    const float* pred = (const float*)d_in[0];
    const float* gt   = (const float*)d_in[1];
    const float* mask = (const float*)d_in[2];
    const float* xyz  = (const float*)d_in[3];
    const int Bcnt = in_sizes[2] / (MU_MAXC * MV_MAXC);   // 1024 samples
    const int NB = 2 * Bcnt;                              // 2 half-sample blocks each

    double* pd = (double*)d_ws;
    float* out = (float*)d_out;

    const size_t need = (size_t)3 * NB * sizeof(double) + (size_t)NB * sizeof(int);
    if (ws_size >= need) {
        int* badp = (int*)(pd + 3 * NB);
        hipLaunchKernelGGL((nurbs_loss_kernel<0>), dim3(NB), dim3(256), 0, stream,
                           pred, gt, mask, xyz, pd, Bcnt, badp);
        hipLaunchKernelGGL(finalize_partials_kernel, dim3(1), dim3(256), 0, stream,
                           pd, badp, out, Bcnt, NB);
    } else {
        int* badp = (int*)(pd + 3);
        hipLaunchKernelGGL(zero_ws_kernel, dim3(1), dim3(1), 0, stream, pd, badp);
        hipLaunchKernelGGL((nurbs_loss_kernel<1>), dim3(NB), dim3(256), 0, stream,
                           pred, gt, mask, xyz, pd, Bcnt, badp);
        hipLaunchKernelGGL(finalize_atomic_kernel, dim3(1), dim3(1), 0, stream,
                           pd, badp, out, Bcnt);
    }
}